// Round 6
// baseline (315.296 us; speedup 1.0000x reference)
//
#include <hip/hip_runtime.h>
#include <hip/hip_bf16.h>

#define N_NODES 20000
#define B 4
#define H 128
#define I_DIM 64
#define E_MAX 320000
#define CAP 64              // padded CSR row capacity (in-deg ~Poisson(16); P(>63) ~ e^-40)

// ---- all scratch in module-static device globals (no d_ws dependence) ----
// g_cnt_dst[n] / g_deg_src[n] are zeroed by fused_kernel's OWN-node epilogue
// (fused reads only its own nodes' counters -> race-free, no contention).
// Zero-init at module load makes run 0 correct as well.
__device__ int   g_cnt_dst[N_NODES];        // atomic cursor == final in-degree
__device__ int   g_deg_src[N_NODES];        // out-degree
__device__ int   g_csr[N_NODES * CAP];      // padded CSR: row n at n*CAP, 5.12 MB
__device__ float g_xg[4 * B * H];
// batch-interleaved bf16 copy of h_prev, PRE-SCALED by dn_src = rsqrt(out_deg):
// g_hs[n*H+h] = {bf16 (h_prev[b][n][h] * dn_src[n]), b=0..3}
__device__ uint2 g_hs[N_NODES * H];

// ---- K1: src-degree histogram (L2-resident 80KB table) + xgate ----
__global__ __launch_bounds__(256)
void degree_kernel(const int* __restrict__ src, int E, int eb,
                   const float* __restrict__ x,
                   const float* __restrict__ Wi, const float* __restrict__ bi,
                   const float* __restrict__ Wf, const float* __restrict__ bf_,
                   const float* __restrict__ Wo, const float* __restrict__ bo,
                   const float* __restrict__ Wc, const float* __restrict__ bc) {
    int blk = blockIdx.x;
    int t = threadIdx.x;
    if (blk < eb) {
        int e = blk * 256 + t;
        if (e < E) atomicAdd(&g_deg_src[src[e]], 1);
    } else {
        int bid = blk - eb;                       // 0..7
        int g = bid >> 1;                         // gate 0..3
        int b = ((bid & 1) << 1) | (t >> 7);      // batch 0..3
        int h = t & 127;
        const float* W;
        const float* bb;
        switch (g) {
            case 0: W = Wi; bb = bi; break;
            case 1: W = Wf; bb = bf_; break;
            case 2: W = Wo; bb = bo; break;
            default: W = Wc; bb = bc; break;
        }
        float acc = bb[h];
#pragma unroll
        for (int i = 0; i < I_DIM; i++)
            acc += x[b * I_DIM + i] * W[i * H + h];
        g_xg[(g * B + b) * H + h] = acc;
    }
}

// ---- K2: pack (dn_src folded into bf16) + padded-CSR place ----
__global__ __launch_bounds__(256)
void mid_kernel(const float* __restrict__ h_prev,
                const int* __restrict__ src, const int* __restrict__ dst, int E) {
    const int PACK_BLKS = (N_NODES * H) / 256;   // 10000, exact
    int blk = blockIdx.x;
    int t = threadIdx.x;

    if (blk < PACK_BLKS) {
        int i = blk * 256 + t;                    // (n*H + h), always in range
        int n = i >> 7;                           // H = 128
        float sc = rsqrtf(fmaxf((float)g_deg_src[n], 1.0f));
        const long stride = (long)N_NODES * H;
        float v0 = h_prev[i] * sc;
        float v1 = h_prev[i + stride] * sc;
        float v2 = h_prev[i + 2 * stride] * sc;
        float v3 = h_prev[i + 3 * stride] * sc;
        __hip_bfloat162 p01 = __float22bfloat162_rn(make_float2(v0, v1));
        __hip_bfloat162 p23 = __float22bfloat162_rn(make_float2(v2, v3));
        uint2 wv;
        wv.x = *reinterpret_cast<unsigned int*>(&p01);
        wv.y = *reinterpret_cast<unsigned int*>(&p23);
        g_hs[i] = wv;
    } else {
        int e = (blk - PACK_BLKS) * 256 + t;
        if (e < E) {
            int d = dst[e];
            int slot = atomicAdd(&g_cnt_dst[d], 1);
            if (slot < CAP) g_csr[(d << 6) + slot] = src[e];
        }
    }
}

__device__ __forceinline__ float fast_sigmoid(float z) {
    return 1.f / (1.f + __expf(-z));
}
__device__ __forceinline__ float fast_tanh(float z) {
    // 1 - 2/(e^{2z}+1): e^{2z}->inf => 1; e^{2z}->0 => -1. No inf/inf NaN path.
    return 1.f - 2.f / (__expf(2.f * z) + 1.f);
}

// ------- K3 fused: 2 nodes/block; CSR gather + split-k matvec + LSTM ---------
// Thread map: t in [0,256); node-slice ni = t>>7; h = t&127; wave-in-slice
// w = (t>>6)&1; lane = t&63.  n = 2*blockIdx.x + ni.
__global__ __launch_bounds__(256)
void fused_kernel(const float* __restrict__ Wg, const float* __restrict__ bg,
                  const float* __restrict__ c_prev,
                  float* __restrict__ out_h, float* __restrict__ out_c) {
    int t = threadIdx.x;
    int ni = t >> 7;
    int h = t & 127;
    int w = (t >> 6) & 1;
    int lane = t & 63;
    int n = (blockIdx.x << 1) + ni;

    int cnt = g_cnt_dst[n];                    // own-node counter: race-free
    float dd = rsqrtf(fmaxf((float)cnt, 1.0f));
    if (cnt > CAP) cnt = CAP;                  // never triggers (safety)

    // Prefetch c_prev (streaming, read-once): issued before the gather so
    // HBM latency hides under it; nontemporal keeps it out of L2 (which is
    // hot with the g_hs gather table).
    const long stride = (long)N_NODES * H;
    float cp[B];
#pragma unroll
    for (int b = 0; b < B; b++)
        cp[b] = __builtin_nontemporal_load(&c_prev[(long)b * stride + (long)n * H + h]);

    // Stage this node's row bases in LDS (one coalesced load by wave 0 of
    // each slice); gather loop fetches them via broadcast ds_read.
    __shared__ int sbase[2][CAP];
    if (h < 64) {
        int s = g_csr[(n << 6) + (lane < cnt ? lane : 0)];  // always valid addr
        sbase[ni][lane] = s << 7;                           // s * H
    }
    __syncthreads();

    float a0 = 0.f, a1 = 0.f, a2 = 0.f, a3 = 0.f;

#define ACC(wv) { \
        __hip_bfloat162 p01 = *reinterpret_cast<__hip_bfloat162*>(&(wv).x); \
        __hip_bfloat162 p23 = *reinterpret_cast<__hip_bfloat162*>(&(wv).y); \
        float2 f01 = __bfloat1622float2(p01); \
        float2 f23 = __bfloat1622float2(p23); \
        a0 += f01.x; a1 += f01.y; a2 += f23.x; a3 += f23.y; }

    // 8-wide unroll: 8 row bases from LDS, then 8 independent row loads in
    // flight before any consumption (avg degree 16).
    const int* sb = sbase[ni];
    int j = 0;
    for (; j + 8 <= cnt; j += 8) {
        int b0 = sb[j];
        int b1 = sb[j + 1];
        int b2 = sb[j + 2];
        int b3 = sb[j + 3];
        int b4 = sb[j + 4];
        int b5 = sb[j + 5];
        int b6 = sb[j + 6];
        int b7 = sb[j + 7];
        uint2 w0 = g_hs[b0 + h];
        uint2 w1 = g_hs[b1 + h];
        uint2 w2 = g_hs[b2 + h];
        uint2 w3 = g_hs[b3 + h];
        uint2 w4 = g_hs[b4 + h];
        uint2 w5 = g_hs[b5 + h];
        uint2 w6 = g_hs[b6 + h];
        uint2 w7 = g_hs[b7 + h];
        ACC(w0); ACC(w1); ACC(w2); ACC(w3);
        ACC(w4); ACC(w5); ACC(w6); ACC(w7);
    }
    for (; j + 4 <= cnt; j += 4) {
        int b0 = sb[j];
        int b1 = sb[j + 1];
        int b2 = sb[j + 2];
        int b3 = sb[j + 3];
        uint2 w0 = g_hs[b0 + h];
        uint2 w1 = g_hs[b1 + h];
        uint2 w2 = g_hs[b2 + h];
        uint2 w3 = g_hs[b3 + h];
        ACC(w0); ACC(w1); ACC(w2); ACC(w3);
    }
    for (; j < cnt; j++) {
        uint2 wv = g_hs[sb[j] + h];
        ACC(wv);
    }
#undef ACC

    a0 *= dd; a1 *= dd; a2 *= dd; a3 *= dd;

    // Publish a-row for the sibling wave's foreign-k half.
    __shared__ float4 arow4[2][H];
    arow4[ni][h] = make_float4(a0, a1, a2, a3);
    __syncthreads();

    float g0 = 0.f, g1 = 0.f, g2 = 0.f, g3 = 0.f;

    // Split-k matvec.
    // Native half: a[k] lives in lane (k-64w) of THIS wave -> v_readlane
    // (VALU path, no LDS-unit pressure). Foreign half: broadcast ds_read.
#pragma unroll 8
    for (int kk = 0; kk < 64; kk++) {
        int k = (w << 6) + kk;
        float wv = Wg[k * H + h];              // coalesced 256B/wave, L2-hot
        float b0 = __int_as_float(__builtin_amdgcn_readlane(__float_as_int(a0), kk));
        float b1 = __int_as_float(__builtin_amdgcn_readlane(__float_as_int(a1), kk));
        float b2 = __int_as_float(__builtin_amdgcn_readlane(__float_as_int(a2), kk));
        float b3 = __int_as_float(__builtin_amdgcn_readlane(__float_as_int(a3), kk));
        g0 += b0 * wv;
        g1 += b1 * wv;
        g2 += b2 * wv;
        g3 += b3 * wv;
    }
#pragma unroll 8
    for (int kk = 0; kk < 64; kk++) {
        int k = ((1 - w) << 6) + kk;
        float4 a = arow4[ni][k];               // broadcast ds_read_b128
        float wv = Wg[k * H + h];
        g0 += a.x * wv;
        g1 += a.y * wv;
        g2 += a.z * wv;
        g3 += a.w * wv;
    }

    float bgh = bg[h];
    float gh_arr[B] = {g0 + bgh, g1 + bgh, g2 + bgh, g3 + bgh};
#pragma unroll
    for (int b = 0; b < B; b++) {
        float gh = gh_arr[b];
        float xi = g_xg[(0 * B + b) * H + h];
        float xf = g_xg[(1 * B + b) * H + h];
        float xo = g_xg[(2 * B + b) * H + h];
        float xc = g_xg[(3 * B + b) * H + h];

        float it = fast_sigmoid(xi + gh);
        float ft = fast_sigmoid(xf + gh);
        float ot = fast_sigmoid(xo + gh);
        float ct = fast_tanh(xc + gh);

        float c  = ft * cp[b] + it * ct;
        float ho = ot * fast_tanh(c);

        long idx = (long)b * stride + (long)n * H + h;
        __builtin_nontemporal_store(ho, &out_h[idx]);
        __builtin_nontemporal_store(c,  &out_c[idx]);
    }

    // Own-node counter zeroing (h==0 fires for t=0 and t=128 -> both nodes).
    if (h == 0)  g_cnt_dst[n] = 0;
    if (h == 64) g_deg_src[n] = 0;
}

extern "C" void kernel_launch(void* const* d_in, const int* in_sizes, int n_in,
                              void* d_out, int out_size, void* d_ws, size_t ws_size,
                              hipStream_t stream) {
    const float* x      = (const float*)d_in[0];
    const float* h_prev = (const float*)d_in[1];
    const float* c_prev = (const float*)d_in[2];
    const int* src = (const int*)d_in[3];
    const int* dst = (const int*)d_in[4];
    const float* Wi = (const float*)d_in[5];
    const float* bi = (const float*)d_in[6];
    const float* Wf = (const float*)d_in[7];
    const float* bf_ = (const float*)d_in[8];
    const float* Wo = (const float*)d_in[9];
    const float* bo = (const float*)d_in[10];
    const float* Wc = (const float*)d_in[11];
    const float* bc = (const float*)d_in[12];
    const float* Wg = (const float*)d_in[13];
    const float* bg = (const float*)d_in[14];

    int E = in_sizes[3];
    if (E > E_MAX) E = E_MAX;   // static scratch bound (setup fixes E=320000)
    int eb = (E + 255) / 256;
    const int PACK_BLKS = (N_NODES * H) / 256;   // 10000

    degree_kernel<<<eb + 8, 256, 0, stream>>>(src, E, eb,
        x, Wi, bi, Wf, bf_, Wo, bo, Wc, bc);
    mid_kernel<<<PACK_BLKS + eb, 256, 0, stream>>>(h_prev, src, dst, E);

    float* out_h = (float*)d_out;
    float* out_c = out_h + (long)B * N_NODES * H;
    fused_kernel<<<N_NODES / 2, 256, 0, stream>>>(Wg, bg, c_prev, out_h, out_c);
}

// Round 7
// 263.187 us; speedup vs baseline: 1.1980x; 1.1980x over previous
//
#include <hip/hip_runtime.h>
#include <hip/hip_bf16.h>

#define N_NODES 20000
#define B 4
#define H 128
#define I_DIM 64
#define E_MAX 320000
#define CAP 64              // padded CSR row capacity (in-deg ~Poisson(16); P(>63) ~ e^-40)

typedef __attribute__((ext_vector_type(8))) short short8;   // 8 bf16 = 4 VGPR (MFMA A/B frag)
typedef __attribute__((ext_vector_type(4))) float float4v;  // MFMA C/D frag

// ---- all scratch in module-static device globals (no d_ws dependence) ----
// g_cnt_dst / g_deg_src zeroed by fused_kernel (own-nodes only, post-barrier).
__device__ int   g_cnt_dst[N_NODES];        // atomic cursor == final in-degree
__device__ int   g_deg_src[N_NODES];        // out-degree
__device__ int   g_csr[N_NODES * CAP];      // padded CSR: row n at n*CAP
__device__ float g_xg[4 * B * H];
// batch-interleaved bf16 h_prev, PRE-SCALED by dn_src: g_hs[n*H+h]={bf16 h*dn, b=0..3}
__device__ __align__(16) uint2 g_hs[N_NODES * H];
// Wg as bf16 in MFMA B-fragment order: idx=((tn*4+kb)*64+lane)*8+j holds
// Wg[kb*32+(lane>>4)*8+j][tn*16+(lane&15)]  -> per-frag load = 1 coalesced dwordx4
__device__ __align__(16) unsigned short g_wgB[H * H];

// ---- K1: src-degree histogram + xgate + Wg bf16 B-frag pack ----
__global__ __launch_bounds__(256)
void degree_kernel(const int* __restrict__ src, int E, int eb,
                   const float* __restrict__ x,
                   const float* __restrict__ Wi, const float* __restrict__ bi,
                   const float* __restrict__ Wf, const float* __restrict__ bf_,
                   const float* __restrict__ Wo, const float* __restrict__ bo,
                   const float* __restrict__ Wc, const float* __restrict__ bc,
                   const float* __restrict__ Wg) {
    int blk = blockIdx.x;
    int t = threadIdx.x;
    if (blk < eb) {
        int e = blk * 256 + t;
        if (e < E) atomicAdd(&g_deg_src[src[e]], 1);
    } else if (blk < eb + 8) {
        int bid = blk - eb;                       // 0..7
        int g = bid >> 1;                         // gate 0..3
        int b = ((bid & 1) << 1) | (t >> 7);      // batch 0..3
        int h = t & 127;
        const float* W;
        const float* bb;
        switch (g) {
            case 0: W = Wi; bb = bi; break;
            case 1: W = Wf; bb = bf_; break;
            case 2: W = Wo; bb = bo; break;
            default: W = Wc; bb = bc; break;
        }
        float acc = bb[h];
#pragma unroll
        for (int i = 0; i < I_DIM; i++)
            acc += x[b * I_DIM + i] * W[i * H + h];
        g_xg[(g * B + b) * H + h] = acc;
    } else {
        // B-fragment pack: 64 blocks x 256 threads = 16384 = H*H elements
        int i = (blk - eb - 8) * 256 + t;
        int tn = i >> 11;
        int rem = i & 2047;
        int kb = rem >> 9;
        int rem2 = rem & 511;
        int lane = rem2 >> 3;
        int j = rem2 & 7;
        int k  = kb * 32 + (lane >> 4) * 8 + j;
        int nn = tn * 16 + (lane & 15);
        __hip_bfloat16 hv = __float2bfloat16(Wg[k * H + nn]);
        g_wgB[i] = *reinterpret_cast<unsigned short*>(&hv);
    }
}

// ---- K2: pack (dn_src folded into bf16) + padded-CSR place ----
__global__ __launch_bounds__(256)
void mid_kernel(const float* __restrict__ h_prev,
                const int* __restrict__ src, const int* __restrict__ dst, int E) {
    const int PACK_BLKS = (N_NODES * H) / 256;   // 10000, exact
    int blk = blockIdx.x;
    int t = threadIdx.x;

    if (blk < PACK_BLKS) {
        int i = blk * 256 + t;                    // (n*H + h)
        int n = i >> 7;                           // H = 128
        float sc = rsqrtf(fmaxf((float)g_deg_src[n], 1.0f));
        const long stride = (long)N_NODES * H;
        float v0 = h_prev[i] * sc;
        float v1 = h_prev[i + stride] * sc;
        float v2 = h_prev[i + 2 * stride] * sc;
        float v3 = h_prev[i + 3 * stride] * sc;
        __hip_bfloat162 p01 = __float22bfloat162_rn(make_float2(v0, v1));
        __hip_bfloat162 p23 = __float22bfloat162_rn(make_float2(v2, v3));
        uint2 wv;
        wv.x = *reinterpret_cast<unsigned int*>(&p01);
        wv.y = *reinterpret_cast<unsigned int*>(&p23);
        g_hs[i] = wv;
    } else {
        int e = (blk - PACK_BLKS) * 256 + t;
        if (e < E) {
            int d = dst[e];
            int slot = atomicAdd(&g_cnt_dst[d], 1);
            if (slot < CAP) g_csr[(d << 6) + slot] = src[e];
        }
    }
}

__device__ __forceinline__ float fast_sigmoid(float z) {
    return 1.f / (1.f + __expf(-z));
}
__device__ __forceinline__ float fast_tanh(float z) {
    return 1.f - 2.f / (__expf(2.f * z) + 1.f);
}
__device__ __forceinline__ unsigned pack2bf(float lo, float hi) {
    __hip_bfloat162 p = __float22bfloat162_rn(make_float2(lo, hi));
    return *reinterpret_cast<unsigned*>(&p);
}

// ------- K3 fused: 4 nodes/block (4 waves); gather + MFMA matvec + LSTM ------
// Wave w owns node n = 4*blockIdx+w. Lane l covers h = 2l, 2l+1 (uint4 loads).
// A-tile rows r = ni*4 + b (16 rows exactly); MFMA C: col=lane&15 -> h,
// row=(lane>>4)*4+reg -> (ni=lane>>4, b=reg).
__global__ __launch_bounds__(256)
void fused_kernel(const float* __restrict__ bg,
                  const float* __restrict__ c_prev,
                  float* __restrict__ out_h, float* __restrict__ out_c) {
    int t = threadIdx.x;
    int w = t >> 6;
    int lane = t & 63;
    int n = (blockIdx.x << 2) + w;
    const long stride = (long)N_NODES * H;

    int cnt = g_cnt_dst[n];                    // own-node counter: race-free
    float dd = rsqrtf(fmaxf((float)cnt, 1.0f));
    if (cnt > CAP) cnt = CAP;

    __shared__ int sbase[4][64];
    __shared__ unsigned short Atile[16][136];  // 272B row stride: 16B-aligned reads

    // Stage row bases (uint4 units): one parallel coalesced load per wave.
    sbase[w][lane] = g_csr[(n << 6) + (lane < cnt ? lane : 0)] << 6;

    // Prefetch c_prev for the epilogue (nontemporal, read-once; latency
    // hides under the gather).
    float cpr[2][4];
    {
        long ne = (long)((blockIdx.x << 2) + (lane >> 4));
#pragma unroll
        for (int i = 0; i < 2; i++) {
            int h = (2 * w + i) * 16 + (lane & 15);
#pragma unroll
            for (int j = 0; j < 4; j++)
                cpr[i][j] = __builtin_nontemporal_load(
                    &c_prev[(long)j * stride + ne * H + h]);
        }
    }

    // ---- gather: h0 = 2*lane, h1 = 2*lane+1, all 4 batches per uint4 ----
    float a0 = 0.f, a1 = 0.f, a2 = 0.f, a3 = 0.f;   // h0, b0..b3
    float a4 = 0.f, a5 = 0.f, a6 = 0.f, a7 = 0.f;   // h1, b0..b3
    const uint4* hs4 = reinterpret_cast<const uint4*>(g_hs);
    const int* sb = sbase[w];

#define ACCV(v) { \
        __hip_bfloat162 p; float2 f; \
        p = *reinterpret_cast<__hip_bfloat162*>(&(v).x); f = __bfloat1622float2(p); a0 += f.x; a1 += f.y; \
        p = *reinterpret_cast<__hip_bfloat162*>(&(v).y); f = __bfloat1622float2(p); a2 += f.x; a3 += f.y; \
        p = *reinterpret_cast<__hip_bfloat162*>(&(v).z); f = __bfloat1622float2(p); a4 += f.x; a5 += f.y; \
        p = *reinterpret_cast<__hip_bfloat162*>(&(v).w); f = __bfloat1622float2(p); a6 += f.x; a7 += f.y; }

    int j = 0;
    for (; j + 8 <= cnt; j += 8) {
        int b0 = sb[j];
        int b1 = sb[j + 1];
        int b2 = sb[j + 2];
        int b3 = sb[j + 3];
        int b4 = sb[j + 4];
        int b5 = sb[j + 5];
        int b6 = sb[j + 6];
        int b7 = sb[j + 7];
        uint4 v0 = hs4[b0 + lane];
        uint4 v1 = hs4[b1 + lane];
        uint4 v2 = hs4[b2 + lane];
        uint4 v3 = hs4[b3 + lane];
        uint4 v4 = hs4[b4 + lane];
        uint4 v5 = hs4[b5 + lane];
        uint4 v6 = hs4[b6 + lane];
        uint4 v7 = hs4[b7 + lane];
        ACCV(v0); ACCV(v1); ACCV(v2); ACCV(v3);
        ACCV(v4); ACCV(v5); ACCV(v6); ACCV(v7);
    }
    for (; j < cnt; j++) {
        uint4 v = hs4[sb[j] + lane];
        ACCV(v);
    }
#undef ACCV

    // ---- scale by dn_dst, pack bf16 into A-tile rows w*4+b ----
    *reinterpret_cast<unsigned*>(&Atile[w * 4 + 0][2 * lane]) = pack2bf(a0 * dd, a4 * dd);
    *reinterpret_cast<unsigned*>(&Atile[w * 4 + 1][2 * lane]) = pack2bf(a1 * dd, a5 * dd);
    *reinterpret_cast<unsigned*>(&Atile[w * 4 + 2][2 * lane]) = pack2bf(a2 * dd, a6 * dd);
    *reinterpret_cast<unsigned*>(&Atile[w * 4 + 3][2 * lane]) = pack2bf(a3 * dd, a7 * dd);

    __syncthreads();

    // counters consumed by all waves above; zero own nodes for next run
    if (t < 4)                 g_cnt_dst[(blockIdx.x << 2) + t] = 0;
    else if (t >= 64 && t < 68) g_deg_src[(blockIdx.x << 2) + (t - 64)] = 0;

    // ---- MFMA: C[16 x 32] per wave (N-tiles 2w, 2w+1), K = 128 in 4 steps --
    int arow = lane & 15;
    int agrp = lane >> 4;
    float4v c0 = {0.f, 0.f, 0.f, 0.f};
    float4v c1 = {0.f, 0.f, 0.f, 0.f};
#pragma unroll
    for (int kb = 0; kb < 4; kb++) {
        short8 af = *reinterpret_cast<const short8*>(&Atile[arow][kb * 32 + agrp * 8]);
        short8 bf0 = *reinterpret_cast<const short8*>(
            &g_wgB[(((2 * w) * 4 + kb) * 64 + lane) * 8]);
        short8 bf1 = *reinterpret_cast<const short8*>(
            &g_wgB[(((2 * w + 1) * 4 + kb) * 64 + lane) * 8]);
        c0 = __builtin_amdgcn_mfma_f32_16x16x32_bf16(af, bf0, c0, 0, 0, 0);
        c1 = __builtin_amdgcn_mfma_f32_16x16x32_bf16(af, bf1, c1, 0, 0, 0);
    }

    // ---- epilogue: C element (reg j, lane) -> (ni=lane>>4, b=j, h) ----
    long ne = (long)((blockIdx.x << 2) + (lane >> 4));
#pragma unroll
    for (int i = 0; i < 2; i++) {
        float4v c = i ? c1 : c0;
        int h = (2 * w + i) * 16 + (lane & 15);
        float bgh = bg[h];
#pragma unroll
        for (int jj = 0; jj < 4; jj++) {
            float gh = c[jj] + bgh;
            float xi = g_xg[(0 * B + jj) * H + h];
            float xf = g_xg[(1 * B + jj) * H + h];
            float xo = g_xg[(2 * B + jj) * H + h];
            float xc = g_xg[(3 * B + jj) * H + h];

            float it = fast_sigmoid(xi + gh);
            float ft = fast_sigmoid(xf + gh);
            float ot = fast_sigmoid(xo + gh);
            float ct = fast_tanh(xc + gh);

            float cc = ft * cpr[i][jj] + it * ct;
            float ho = ot * fast_tanh(cc);

            long idx = (long)jj * stride + ne * H + h;
            __builtin_nontemporal_store(ho, &out_h[idx]);
            __builtin_nontemporal_store(cc, &out_c[idx]);
        }
    }
}

extern "C" void kernel_launch(void* const* d_in, const int* in_sizes, int n_in,
                              void* d_out, int out_size, void* d_ws, size_t ws_size,
                              hipStream_t stream) {
    const float* x      = (const float*)d_in[0];
    const float* h_prev = (const float*)d_in[1];
    const float* c_prev = (const float*)d_in[2];
    const int* src = (const int*)d_in[3];
    const int* dst = (const int*)d_in[4];
    const float* Wi = (const float*)d_in[5];
    const float* bi = (const float*)d_in[6];
    const float* Wf = (const float*)d_in[7];
    const float* bf_ = (const float*)d_in[8];
    const float* Wo = (const float*)d_in[9];
    const float* bo = (const float*)d_in[10];
    const float* Wc = (const float*)d_in[11];
    const float* bc = (const float*)d_in[12];
    const float* Wg = (const float*)d_in[13];
    const float* bg = (const float*)d_in[14];

    int E = in_sizes[3];
    if (E > E_MAX) E = E_MAX;   // static scratch bound (setup fixes E=320000)
    int eb = (E + 255) / 256;
    const int PACK_BLKS = (N_NODES * H) / 256;   // 10000

    degree_kernel<<<eb + 8 + 64, 256, 0, stream>>>(src, E, eb,
        x, Wi, bi, Wf, bf_, Wo, bo, Wc, bc, Wg);
    mid_kernel<<<PACK_BLKS + eb, 256, 0, stream>>>(h_prev, src, dst, E);

    float* out_h = (float*)d_out;
    float* out_c = out_h + (long)B * N_NODES * H;
    fused_kernel<<<N_NODES / 4, 256, 0, stream>>>(bg, c_prev, out_h, out_c);
}